// Round 1
// baseline (437.519 us; speedup 1.0000x reference)
//
#include <hip/hip_runtime.h>

// AdEx neuron simulation: T=500 steps, N=100000 neurons.
// One thread per neuron: state (v, c, ref) lives in registers, loop over T.
// I reads and v_trace writes are coalesced (thread n -> column n).
// Numerics: contract(off) + left-to-right order to match the numpy f32 ref
// (a spike flip costs ~2e-2 >> 1.65e-3 threshold, so rounding parity matters).

__global__ __launch_bounds__(256) void adex_kernel(
    const float* __restrict__ I,
    const float* __restrict__ v0,
    const float* __restrict__ c0,
    const int*   __restrict__ ref0,
    float*       __restrict__ out,
    int N, int T)
{
#pragma clang fp contract(off)
    // Constants: computed in double (Python scalar semantics), cast to f32
    // (jax weak-type demotion when combined with f32 arrays).
    const float EL      = (float)(-70.6e-3);
    const float VT      = (float)(-50.4e-3);
    const float DELTAT  = (float)(2e-3);
    const float NEG_GL  = (float)(-30e-9);
    const float GLDT    = (float)(30e-9 * 2e-3);        // GL*DELTAT (double mul, then cast)
    const float DT_CM   = (float)(1e-3 / 281e-12);      // DT/CM
    const float DT_TAUW = (float)(1e-3 / 144e-3);       // DT/TAUW
    const float Af      = (float)(4e-9);
    const float Bf      = (float)(0.0805e-9);
    const int   REF_STEPS = 2;

    int n = blockIdx.x * blockDim.x + threadIdx.x;
    if (n >= N) return;

    float v  = v0[n];
    float c  = c0[n];
    int   rf = ref0[n];

    size_t idx = (size_t)n;
#pragma unroll 4
    for (int t = 0; t < T; ++t, idx += (size_t)N) {
        float It = I[idx];

        bool  in_ref = rf > 0;
        float v_eff  = in_ref ? EL : v;

        // exp_term = GL*DELTAT * exp(min((v_eff - VT)/DELTAT, 15.0))
        float arg      = fminf((v_eff - VT) / DELTAT, 15.0f);
        float exp_term = GLDT * expf(arg);

        // dv = (DT/CM) * (-GL*(v_eff-EL) + exp_term - c + I_t), left-to-right
        float acc = NEG_GL * (v_eff - EL);
        acc = acc + exp_term;
        acc = acc - c;
        acc = acc + It;
        float dv = DT_CM * acc;

        float v_new = in_ref ? EL : (v_eff + dv);

        // c_new = c + (DT/TAUW) * (A*(v_eff-EL) - c)
        float c_new = c + DT_TAUW * ((Af * (v_eff - EL)) - c);

        bool spike = v_new >= VT;
        float v_out = spike ? EL : v_new;

        c  = spike ? (c_new + Bf) : c_new;
        rf = spike ? REF_STEPS : (in_ref ? rf - 1 : 0);
        v  = v_out;

        out[idx] = v_out;
    }
}

extern "C" void kernel_launch(void* const* d_in, const int* in_sizes, int n_in,
                              void* d_out, int out_size, void* d_ws, size_t ws_size,
                              hipStream_t stream) {
    const float* I    = (const float*)d_in[0];
    const float* v0   = (const float*)d_in[1];
    const float* c0   = (const float*)d_in[2];
    const int*   ref0 = (const int*)d_in[3];
    float*       out  = (float*)d_out;

    int N = in_sizes[1];            // 100000
    int T = in_sizes[0] / N;        // 500

    dim3 block(256);
    dim3 grid((N + 255) / 256);     // 391 blocks = 1564 waves ~ 6 waves/CU
    adex_kernel<<<grid, block, 0, stream>>>(I, v0, c0, ref0, out, N, T);
}

// Round 2
// 351.775 us; speedup vs baseline: 1.2437x; 1.2437x over previous
//
#include <hip/hip_runtime.h>

// AdEx neuron simulation: T=500 steps, N=100000 neurons. One thread per neuron.
// R2: depth-10 software-pipelined register ring buffer for I loads.
//   R1 was latency-bound (1.45 TB/s, VALUBusy 31%, 1.5 waves/SIMD): ~1 load in
//   flight per thread. Depth-10 prefetch puts ~4 MB in flight (> 2.8 MB
//   Little's-law requirement for 6.3 TB/s @ ~900 cyc), all ring indices are
//   compile-time so no scratch. Stores are nontemporal (write-once stream,
//   keeps I resident in L3 — harness restore leaves ~half of I there).
// Numerics: contract(off) + left-to-right order to match numpy f32 ref
//   (a spike flip costs ~2e-2 >> 1.65e-3 threshold).

#define DEPTH 10

__global__ __launch_bounds__(256) void adex_kernel(
    const float* __restrict__ I,
    const float* __restrict__ v0,
    const float* __restrict__ c0,
    const int*   __restrict__ ref0,
    float*       __restrict__ out,
    int N, int T)
{
#pragma clang fp contract(off)
    const float EL      = (float)(-70.6e-3);
    const float VT      = (float)(-50.4e-3);
    const float DELTAT  = (float)(2e-3);
    const float NEG_GL  = (float)(-30e-9);
    const float GLDT    = (float)(30e-9 * 2e-3);        // GL*DELTAT
    const float DT_CM   = (float)(1e-3 / 281e-12);      // DT/CM
    const float DT_TAUW = (float)(1e-3 / 144e-3);       // DT/TAUW
    const float Af      = (float)(4e-9);
    const float Bf      = (float)(0.0805e-9);
    const int   REF_STEPS = 2;

    int n = blockIdx.x * blockDim.x + threadIdx.x;
    if (n >= N) return;

    float v  = v0[n];
    float c  = c0[n];
    int   rf = ref0[n];

    size_t stride    = (size_t)N;
    size_t load_idx  = (size_t)n;
    size_t store_idx = (size_t)n;

    // One simulation step. Updates v, c, rf; returns v_out.
    auto step = [&](float It) -> float {
        bool  in_ref = rf > 0;
        float v_eff  = in_ref ? EL : v;

        float arg      = fminf((v_eff - VT) / DELTAT, 15.0f);
        float exp_term = GLDT * __expf(arg) ; // NOTE: replaced below if precision insufficient
        // Use precise expf for numpy parity:
        exp_term = GLDT * expf(arg);

        float acc = NEG_GL * (v_eff - EL);
        acc = acc + exp_term;
        acc = acc - c;
        acc = acc + It;
        float dv = DT_CM * acc;

        float v_new = in_ref ? EL : (v_eff + dv);
        float c_new = c + DT_TAUW * ((Af * (v_eff - EL)) - c);

        bool  spike = v_new >= VT;
        float v_out = spike ? EL : v_new;

        c  = spike ? (c_new + Bf) : c_new;
        rf = spike ? REF_STEPS : (in_ref ? rf - 1 : 0);
        v  = v_out;
        return v_out;
    };

    float buf[DEPTH];

    // Prologue: preload first DEPTH values (predicated for tiny-T safety).
#pragma unroll
    for (int k = 0; k < DEPTH; ++k) {
        if (k < T) { buf[k] = I[load_idx]; load_idx += stride; }
    }

    int t = 0;
    // Main pipelined loop: each group computes DEPTH steps and prefetches the
    // next DEPTH I-values. Group at t loads indices t+DEPTH .. t+2*DEPTH-1,
    // valid while t + 2*DEPTH <= T. All ring indices compile-time.
    for (; t + 2 * DEPTH <= T; t += DEPTH) {
#pragma unroll
        for (int j = 0; j < DEPTH; ++j) {
            float It = buf[j];
            buf[j] = I[load_idx]; load_idx += stride;   // prefetch t + j + DEPTH
            float v_out = step(It);
            __builtin_nontemporal_store(v_out, &out[store_idx]);
            store_idx += stride;
        }
    }

    // Epilogue: up to 2*DEPTH-1 remaining steps, fully unrolled + predicated
    // (compile-time buffer indices; prefetch only while in range).
#pragma unroll
    for (int j = 0; j < 2 * DEPTH; ++j) {
        if (t + j < T) {
            float It = buf[j % DEPTH];
            if (t + j + DEPTH < T) { buf[j % DEPTH] = I[load_idx]; load_idx += stride; }
            float v_out = step(It);
            __builtin_nontemporal_store(v_out, &out[store_idx]);
            store_idx += stride;
        }
    }
}

extern "C" void kernel_launch(void* const* d_in, const int* in_sizes, int n_in,
                              void* d_out, int out_size, void* d_ws, size_t ws_size,
                              hipStream_t stream) {
    const float* I    = (const float*)d_in[0];
    const float* v0   = (const float*)d_in[1];
    const float* c0   = (const float*)d_in[2];
    const int*   ref0 = (const int*)d_in[3];
    float*       out  = (float*)d_out;

    int N = in_sizes[1];            // 100000
    int T = in_sizes[0] / N;        // 500

    dim3 block(256);
    dim3 grid((N + 255) / 256);     // 391 blocks = 1564 waves
    adex_kernel<<<grid, block, 0, stream>>>(I, v0, c0, ref0, out, N, T);
}

// Round 3
// 347.163 us; speedup vs baseline: 1.2603x; 1.0133x over previous
//
#include <hip/hip_runtime.h>

// AdEx neuron simulation: T=500 steps, N=100000 neurons. One thread per neuron.
// R3 changes vs R2 (129 us, 2.33 TB/s, VALUBusy 48%):
//  1. block 256 -> 64: with 391x256 blocks, 135 CUs got 8 waves / 121 got 4 ->
//     dur set by the 8-wave CUs (~1.26x inflation). 1563 one-wave blocks give
//     every CU 6-7 waves.
//  2. fast faithful f32 division (mul + 2 fma Newton) replaces the ~9-instr
//     v_div_scale/div_fmas/div_fixup sequence: cuts ~6 instrs and ~20 cyc off
//     the per-step critical path. <=1 ulp diff in rare cases — same order as
//     the existing expf-vs-np.exp perturbation (absmax 4.9e-4 vs 1.65e-3 thr).
//  3. DEPTH 10 -> 12 prefetch ring; single u32 byte-offset for I and out.
// Numerics: contract(off), left-to-right order, precise expf (an exp2-fold
// shortcut would ~4x the perturbation -> est. 2e-3 > threshold; not taken).

#define DEPTH 12

__global__ __launch_bounds__(64) void adex_kernel(
    const float* __restrict__ I,
    const float* __restrict__ v0,
    const float* __restrict__ c0,
    const int*   __restrict__ ref0,
    float*       __restrict__ out,
    int N, int T)
{
#pragma clang fp contract(off)
    const float EL       = (float)(-70.6e-3);
    const float VT       = (float)(-50.4e-3);
    const float DELTAT   = (float)(2e-3);
    const float R_DELTAT = (float)(1.0 / (double)((float)(2e-3)));  // fl(1/d)
    const float NEG_GL   = (float)(-30e-9);
    const float GLDT     = (float)(30e-9 * 2e-3);        // GL*DELTAT
    const float DT_CM    = (float)(1e-3 / 281e-12);      // DT/CM
    const float DT_TAUW  = (float)(1e-3 / 144e-3);       // DT/TAUW
    const float Af       = (float)(4e-9);
    const float Bf       = (float)(0.0805e-9);
    const int   REF_STEPS = 2;

    int n = blockIdx.x * blockDim.x + threadIdx.x;
    if (n >= N) return;

    float v  = v0[n];
    float c  = c0[n];
    int   rf = ref0[n];

    const unsigned stride_b = (unsigned)N * 4u;
    unsigned load_off  = (unsigned)n * 4u;
    unsigned store_off = load_off;

    auto ld = [&](unsigned off) -> float {
        return *(const float*)((const char*)I + off);
    };
    auto st = [&](unsigned off, float val) {
        __builtin_nontemporal_store(val, (float*)((char*)out + off));
    };

    // One simulation step. Updates v, c, rf; returns v_out.
    auto step = [&](float It) -> float {
        bool  in_ref = rf > 0;
        float v_eff  = in_ref ? EL : v;

        // arg = (v_eff - VT) / DELTAT  — Newton/fma faithful division
        float x   = v_eff - VT;
        float y0  = x * R_DELTAT;
        float e   = fmaf(-DELTAT, y0, x);
        float arg = fmaf(e, R_DELTAT, y0);
        arg = fminf(arg, 15.0f);
        float exp_term = GLDT * expf(arg);

        float acc = NEG_GL * (v_eff - EL);
        acc = acc + exp_term;
        acc = acc - c;
        acc = acc + It;
        float dv = DT_CM * acc;

        float v_new = in_ref ? EL : (v_eff + dv);
        float c_new = c + DT_TAUW * ((Af * (v_eff - EL)) - c);

        bool  spike = v_new >= VT;
        float v_out = spike ? EL : v_new;

        c  = spike ? (c_new + Bf) : c_new;
        rf = spike ? REF_STEPS : (in_ref ? rf - 1 : 0);
        v  = v_out;
        return v_out;
    };

    float buf[DEPTH];

    // Prologue: preload first DEPTH values (predicated for tiny-T safety).
#pragma unroll
    for (int k = 0; k < DEPTH; ++k) {
        if (k < T) { buf[k] = ld(load_off); load_off += stride_b; }
    }

    int t = 0;
    // Main pipelined loop: consume buf[j] (loaded DEPTH steps ago), prefetch
    // step t+j+DEPTH into the same slot. All ring indices compile-time.
    for (; t + 2 * DEPTH <= T; t += DEPTH) {
#pragma unroll
        for (int j = 0; j < DEPTH; ++j) {
            float It = buf[j];
            buf[j] = ld(load_off); load_off += stride_b;
            float v_out = step(It);
            st(store_off, v_out);
            store_off += stride_b;
        }
    }

    // Epilogue: up to 2*DEPTH-1 remaining steps, unrolled + predicated.
#pragma unroll
    for (int j = 0; j < 2 * DEPTH; ++j) {
        if (t + j < T) {
            float It = buf[j % DEPTH];
            if (t + j + DEPTH < T) { buf[j % DEPTH] = ld(load_off); load_off += stride_b; }
            float v_out = step(It);
            st(store_off, v_out);
            store_off += stride_b;
        }
    }
}

extern "C" void kernel_launch(void* const* d_in, const int* in_sizes, int n_in,
                              void* d_out, int out_size, void* d_ws, size_t ws_size,
                              hipStream_t stream) {
    const float* I    = (const float*)d_in[0];
    const float* v0   = (const float*)d_in[1];
    const float* c0   = (const float*)d_in[2];
    const int*   ref0 = (const int*)d_in[3];
    float*       out  = (float*)d_out;

    int N = in_sizes[1];            // 100000
    int T = in_sizes[0] / N;        // 500

    dim3 block(64);
    dim3 grid((N + 63) / 64);       // 1563 one-wave blocks -> 6-7 waves/CU, even
    adex_kernel<<<grid, block, 0, stream>>>(I, v0, c0, ref0, out, N, T);
}